// Round 6
// baseline (313.200 us; speedup 1.0000x reference)
//
#include <hip/hip_runtime.h>

// PoolingNms fused: 3 chained pool/unpool (k=3,5,6) on 16x1x1080x1920 fp32.
// After stage 1 the tensor is sparse (<=1 survivor per 3x3 cell, at its own
// position); stages 2/3 are pure filters over survivors. lcm(3,5,6)=30 |
// 1080,1920 -> 30x30 supertiles independent. Tie-break: packed (r<<5)|c
// ascending == row-major first-occurrence == jnp.argmax, bit-exact.
//
// R6: R1-R5 all plateaued ~92us because load/compute/store phases were
// separated by block barriers -> resident blocks convoy and the three pipes
// (VALU 31% + LDS 27% + HBM 46%) run SEQUENTIALLY (sum==measured cycles).
// Fix: everything is per-wave, so drop __syncthreads entirely (same-wave LDS
// ops are ordered; wave_barrier() pins compiler motion), make waves
// persistent (1536 blocks x 4 waves x 6 tiles each = 36864 supertiles,
// exact), and prefetch tile j+1's window loads into registers before tile
// j's filter/compose/store so memory stays busy under compute.

#define H 1080
#define W 1920
#define NT 256
#define NBLK 1536  // 6 blocks/CU, all co-resident (LDS 18.75KB -> cap 8)
#define TPW 6      // supertiles per wave: 1536*4*6 = 36864 = 36*64*16 exact

__global__ __launch_bounds__(NT, 6) void pooling_nms_kernel(
    const float* __restrict__ x, float* __restrict__ out) {
    __shared__ float sv[4][100];   // per-wave stage-1 survivor values
    __shared__ int   sp[4][100];   // packed (r<<5)|c, supertile-local
    __shared__ float w5v[4][36];   // per-wave 5x5 winners
    __shared__ int   w5p[4][36];
    __shared__ float comp[4][900]; // per-wave 30x30 compose tile

    const int t = threadIdx.x;
    const int w = t >> 6;
    const int ln = t & 63;

    // ---- lane-constant maps (computed once; loops below are div-free).
    const int wr0 = ln / 10, wc0 = ln - wr0 * 10;        // window ln
    const int wn1 = 64 + ln;
    const int wr1 = wn1 / 10, wc1 = wn1 - wr1 * 10;      // window 64+ln (ln<36)
    const long off0 = (long)(wr0 * 3) * W + wc0 * 3;
    const long off1 = (long)(wr1 * 3) * W + wc1 * 3;
    const int sr = ln / 15, sc = ln - sr * 15;           // store map (ln<60)
    const int p2a = ln / 6, p2b = ln - p2a * 6;          // 5x5 cell (ln<36)
    const int rlo2 = (5 * p2a) / 3, rhi2 = (5 * p2a + 4) / 3;
    const int clo2 = (5 * p2b) / 3, chi2 = (5 * p2b + 4) / 3;
    const int p3a = ln / 5, p3b = ln - p3a * 5;          // 6x6 cell (ln<25)
    const int rlo3 = (6 * p3a) / 5, clo3 = (6 * p3b) / 5;

    const int wid = blockIdx.x * 4 + w;
    int s = wid * TPW;  // supertile id: row = s/64 (of 576 = 36*16), col = s%64

    auto base_of = [&](int ss) -> size_t {
        const int str = ss >> 6, stc = ss & 63;
        const int b = str / 36, r30 = str - b * 36;
        return (size_t)b * ((size_t)H * W) + (size_t)(r30 * 30) * W +
               (size_t)stc * 30;
    };

    size_t base = base_of(s);
    float va[9], vb[9];
    // ---- prologue: loads for tile 0 (merge to dwordx3 per row).
    {
        const float* p0 = x + base + off0;
#pragma unroll
        for (int r = 0; r < 3; ++r) {
            va[r * 3 + 0] = p0[(size_t)r * W + 0];
            va[r * 3 + 1] = p0[(size_t)r * W + 1];
            va[r * 3 + 2] = p0[(size_t)r * W + 2];
        }
        if (ln < 36) {
            const float* p1 = x + base + off1;
#pragma unroll
            for (int r = 0; r < 3; ++r) {
                vb[r * 3 + 0] = p1[(size_t)r * W + 0];
                vb[r * 3 + 1] = p1[(size_t)r * W + 1];
                vb[r * 3 + 2] = p1[(size_t)r * W + 2];
            }
        }
    }

    for (int j = 0; j < TPW; ++j) {
        const size_t curbase = base;

        // ---- stage 1 (k=3) from registers -> per-wave tables.
        {
            float mx = -1.0f; int am = 0;
#pragma unroll
            for (int r = 0; r < 3; ++r)
#pragma unroll
                for (int c = 0; c < 3; ++c) {
                    const float v = va[r * 3 + c];
                    if (v > mx) { mx = v; am = ((wr0 * 3 + r) << 5) | (wc0 * 3 + c); }
                }
            sv[w][ln] = mx; sp[w][ln] = am;
            if (ln < 36) {
                mx = -1.0f; am = 0;
#pragma unroll
                for (int r = 0; r < 3; ++r)
#pragma unroll
                    for (int c = 0; c < 3; ++c) {
                        const float v = vb[r * 3 + c];
                        if (v > mx) { mx = v; am = ((wr1 * 3 + r) << 5) | (wc1 * 3 + c); }
                    }
                sv[w][wn1] = mx; sp[w][wn1] = am;
            }
        }

        // ---- prefetch next tile's windows (in flight across phases 2-4).
        if (j + 1 < TPW) {
            ++s;
            base = base_of(s);
            const float* p0 = x + base + off0;
#pragma unroll
            for (int r = 0; r < 3; ++r) {
                va[r * 3 + 0] = p0[(size_t)r * W + 0];
                va[r * 3 + 1] = p0[(size_t)r * W + 1];
                va[r * 3 + 2] = p0[(size_t)r * W + 2];
            }
            if (ln < 36) {
                const float* p1 = x + base + off1;
#pragma unroll
                for (int r = 0; r < 3; ++r) {
                    vb[r * 3 + 0] = p1[(size_t)r * W + 0];
                    vb[r * 3 + 1] = p1[(size_t)r * W + 1];
                    vb[r * 3 + 2] = p1[(size_t)r * W + 2];
                }
            }
        }
        __builtin_amdgcn_wave_barrier();  // same-wave LDS order; no s_barrier

        // ---- stage 2 (k=5): winner among stage-1 survivors per 5x5 cell.
        if (ln < 36) {
            float bv = -1.0f; int bp = 0x7FFFFFFF;
            for (int r3 = rlo2; r3 <= rhi2; ++r3)
                for (int c3 = clo2; c3 <= chi2; ++c3) {
                    const int idx = r3 * 10 + c3;
                    const float v = sv[w][idx];
                    const int p = sp[w][idx];
                    const int r = p >> 5, c = p & 31;
                    const bool in = ((unsigned)(r - 5 * p2a) < 5u) &
                                    ((unsigned)(c - 5 * p2b) < 5u);
                    if (in && (v > bv || (v == bv && p < bp))) { bv = v; bp = p; }
                }
            w5v[w][ln] = bv;  // -1 if cell empty
            w5p[w][ln] = bp;
        }
        __builtin_amdgcn_wave_barrier();

        // ---- zero compose tile (float4; same-wave WAW order vs scatter).
        float4* c4 = reinterpret_cast<float4*>(comp[w]);
#pragma unroll
        for (int k2 = 0; k2 < 4; ++k2) {
            const int i = ln + 64 * k2;
            if (i < 225) c4[i] = make_float4(0.f, 0.f, 0.f, 0.f);
        }

        // ---- stage 3 (k=6): 4 candidate 5-cells; winners scatter to comp.
        if (ln < 25) {
            float bv = -1.0f; int bp = 0x7FFFFFFF;
#pragma unroll
            for (int dr = 0; dr < 2; ++dr)
#pragma unroll
                for (int dc = 0; dc < 2; ++dc) {
                    const int idx = (rlo3 + dr) * 6 + (clo3 + dc);
                    const float v = w5v[w][idx];
                    const int p = w5p[w][idx];
                    const int r = p >> 5, c = p & 31;
                    const bool in = (v >= 0.0f) &
                                    ((unsigned)(r - 6 * p3a) < 6u) &
                                    ((unsigned)(c - 6 * p3b) < 6u);
                    if (in && (v > bv || (v == bv && p < bp))) { bv = v; bp = p; }
                }
            if (bv >= 0.0f) comp[w][(bp >> 5) * 30 + (bp & 31)] = bv;
        }
        __builtin_amdgcn_wave_barrier();

        // ---- store: 60 lanes cover 4 rows/iter as float2 (8B-aligned:
        // col base = 120B*stc, row pitch 7680B).
        if (ln < 60) {
            float* d = out + curbase + (size_t)sr * W + sc * 2;
            const float* cb = &comp[w][sr * 30 + sc * 2];
#pragma unroll
            for (int k2 = 0; k2 < 8; ++k2) {
                const int r = sr + 4 * k2;
                if (r < 30) {
                    const float2 v2 = *reinterpret_cast<const float2*>(cb + 120 * k2);
                    *reinterpret_cast<float2*>(d + (size_t)(4 * k2) * W) = v2;
                }
            }
        }
        __builtin_amdgcn_wave_barrier();  // comp reads before next tile's zero
    }
}

extern "C" void kernel_launch(void* const* d_in, const int* in_sizes, int n_in,
                              void* d_out, int out_size, void* d_ws, size_t ws_size,
                              hipStream_t stream) {
    const float* x = (const float*)d_in[0];
    float* out = (float*)d_out;
    pooling_nms_kernel<<<dim3(NBLK, 1, 1), NT, 0, stream>>>(x, out);
}